// Round 3
// baseline (18251.181 us; speedup 1.0000x reference)
//
#include <hip/hip_runtime.h>
#include <hip/hip_bf16.h>

// ---------------------------------------------------------------------------
// CorrectTransformerAdaptor: downsample MLP + 2 transformer layers.
// Round 2: dtype-agnostic correctness. A probe kernel detects whether the
// harness supplied f32 (reference dtype) or bf16 buffers; all input/output
// accesses dispatch on that device-side flag. Scratch is always bf16 with
// fp32 accumulation. Residual stream X lives in d_out (flag dtype).
// Batch-chunked (c in {8,4,2,1}) so ws needs only 8*c MB.
// ---------------------------------------------------------------------------

#define DMODEL 1024
#define DFF 2048
#define FHID 256
#define NHEAD 8
#define DKH 128
#define TSEQ 1024

typedef __hip_bfloat16 bf16;

__device__ int g_is_bf16;

__device__ __forceinline__ bool flagbf() {
    return __hip_atomic_load(&g_is_bf16, __ATOMIC_ACQUIRE,
                             __HIP_MEMORY_SCOPE_AGENT) != 0;
}
__device__ __forceinline__ float gload(const void* p, size_t i, bool bf) {
    return bf ? __bfloat162float(((const bf16*)p)[i]) : ((const float*)p)[i];
}
__device__ __forceinline__ void gstore(void* p, size_t i, bool bf, float v) {
    if (bf) ((bf16*)p)[i] = __float2bfloat16(v);
    else    ((float*)p)[i] = v;
}

// ---- dtype probe: bf16 halves of genuine bf16 weights are all tiny; ------
// ---- f32-backed data read as bf16 halves contains huge/NaN values. -------
__global__ void detect_kernel(const void* __restrict__ probe) {
    if (threadIdx.x == 0 && blockIdx.x == 0) {
        const bf16* h = (const bf16*)probe;
        int isbf = 1;
        for (int i = 0; i < 256; ++i) {
            float v = __bfloat162float(h[i]);
            if (!(fabsf(v) <= 1000.0f)) isbf = 0;  // catches huge AND NaN
        }
        __hip_atomic_store(&g_is_bf16, isbf, __ATOMIC_RELEASE,
                           __HIP_MEMORY_SCOPE_AGENT);
    }
}

// ---------------- block reduction helpers (256-thread blocks) --------------
__device__ __forceinline__ float block_reduce_sum(float v, float* red) {
    int tid = threadIdx.x;
    red[tid] = v;
    __syncthreads();
    #pragma unroll
    for (int s = 128; s > 0; s >>= 1) {
        if (tid < s) red[tid] += red[tid + s];
        __syncthreads();
    }
    float r = red[0];
    __syncthreads();
    return r;
}

__device__ __forceinline__ float block_reduce_max(float v, float* red) {
    int tid = threadIdx.x;
    red[tid] = v;
    __syncthreads();
    #pragma unroll
    for (int s = 128; s > 0; s >>= 1) {
        if (tid < s) red[tid] = fmaxf(red[tid], red[tid + s]);
        __syncthreads();
    }
    float r = red[0];
    __syncthreads();
    return r;
}

// ---------------- GEMM: C[M,N] = op(A[M,K] @ W[N,K]^T + bias) --------------
// 64x64 tile, 16x16 threads, 4x4 per thread, K-step 16, fp32 accumulate.
// AMODE/CMODE: 0 = fixed bf16 (scratch), 1 = flag dtype (harness buffer).
template <int AMODE, int CMODE, bool RELU, bool ADD>
__global__ __launch_bounds__(256) void gemm_kernel(
        const void* __restrict__ A, size_t a_off,
        const void* __restrict__ W, size_t w_off,
        const void* __restrict__ bias, size_t b_off,
        void* __restrict__ C, size_t c_off,
        int M, int N, int K) {
    const bool fl  = flagbf();
    const bool abf = AMODE ? fl : true;
    const bool cbf = CMODE ? fl : true;

    __shared__ float As[16][65];  // [kk][m]
    __shared__ float Bs[16][65];  // [kk][n]
    const int bm = blockIdx.y * 64;
    const int bn = blockIdx.x * 64;
    const int tx = threadIdx.x, ty = threadIdx.y;  // 16 x 16
    const int tid = ty * 16 + tx;

    float acc[4][4] = {};

    for (int k0 = 0; k0 < K; k0 += 16) {
        {
            int m = tid >> 2;
            int kk = (tid & 3) * 4;
            size_t src = a_off + (size_t)(bm + m) * K + k0 + kk;
            #pragma unroll
            for (int i = 0; i < 4; ++i) As[kk + i][m] = gload(A, src + i, abf);
        }
        {
            int n = tid >> 2;
            int kk = (tid & 3) * 4;
            size_t src = w_off + (size_t)(bn + n) * K + k0 + kk;
            #pragma unroll
            for (int i = 0; i < 4; ++i) Bs[kk + i][n] = gload(W, src + i, fl);
        }
        __syncthreads();
        #pragma unroll
        for (int kk = 0; kk < 16; ++kk) {
            float a[4], b[4];
            #pragma unroll
            for (int i = 0; i < 4; ++i) a[i] = As[kk][ty * 4 + i];
            #pragma unroll
            for (int j = 0; j < 4; ++j) b[j] = Bs[kk][tx * 4 + j];
            #pragma unroll
            for (int i = 0; i < 4; ++i)
                #pragma unroll
                for (int j = 0; j < 4; ++j) acc[i][j] = fmaf(a[i], b[j], acc[i][j]);
        }
        __syncthreads();
    }

    #pragma unroll
    for (int i = 0; i < 4; ++i) {
        int m = bm + ty * 4 + i;
        #pragma unroll
        for (int j = 0; j < 4; ++j) {
            int n = bn + tx * 4 + j;
            float v = acc[i][j] + gload(bias, b_off + n, fl);
            if (RELU) v = fmaxf(v, 0.f);
            size_t idx = c_off + (size_t)m * N + n;
            if (ADD) v += gload(C, idx, cbf);
            gstore(C, idx, cbf, v);
        }
    }
}

// ---------------- LayerNorm (row of 1024 per block) ------------------------
__global__ __launch_bounds__(256) void ln_kernel(
        const void* __restrict__ X, size_t x_off,
        const void* __restrict__ g, const void* __restrict__ b, size_t gb_off,
        bf16* __restrict__ H) {
    const bool fl = flagbf();
    const int D = DMODEL;
    __shared__ float xs[DMODEL];
    __shared__ float red[256];
    const int row = blockIdx.x, tid = threadIdx.x;
    const size_t xrow = x_off + (size_t)row * D;

    float s = 0.f;
    for (int i = tid; i < D; i += 256) { float v = gload(X, xrow + i, fl); xs[i] = v; s += v; }
    float mean = block_reduce_sum(s, red) * (1.f / D);

    float vs = 0.f;
    for (int i = tid; i < D; i += 256) { float d = xs[i] - mean; vs += d * d; }
    float var = block_reduce_sum(vs, red) * (1.f / D);
    float rstd = rsqrtf(var + 1e-12f);

    bf16* h = H + (size_t)row * D;
    for (int i = tid; i < D; i += 256)
        h[i] = __float2bfloat16((xs[i] - mean) * rstd * gload(g, gb_off + i, fl)
                                + gload(b, gb_off + i, fl));
}

// ---------------- Attention: one block per (local batch, head, q) ----------
__global__ __launch_bounds__(256) void attn_kernel(
        const bf16* __restrict__ Qm, const bf16* __restrict__ Km,
        const bf16* __restrict__ Vm, bf16* __restrict__ Om) {
    const int q = blockIdx.x, h = blockIdx.y, bb = blockIdx.z;
    const int tid = threadIdx.x;
    __shared__ float qv[DKH];
    __shared__ float sc[TSEQ];
    __shared__ float red[256];

    const size_t base = ((size_t)bb * TSEQ) * DMODEL + (size_t)h * DKH;

    if (tid < DKH) qv[tid] = __bfloat162float(Qm[base + (size_t)q * DMODEL + tid]);
    __syncthreads();

    const float scale = 0.08838834764831845f;  // 1/sqrt(128)
    for (int k = tid; k < TSEQ; k += 256) {
        const bf16* kp = Km + base + (size_t)k * DMODEL;
        float acc = 0.f;
        #pragma unroll 8
        for (int d = 0; d < DKH; ++d) acc = fmaf(qv[d], __bfloat162float(kp[d]), acc);
        sc[k] = acc * scale;
    }

    float m = -1e30f;
    for (int k = tid; k < TSEQ; k += 256) m = fmaxf(m, sc[k]);
    m = block_reduce_max(m, red);

    float s = 0.f;
    for (int k = tid; k < TSEQ; k += 256) {
        float p = expf(sc[k] - m);
        sc[k] = p;
        s += p;
    }
    float inv = 1.f / block_reduce_sum(s, red);

    const int d = tid & (DKH - 1);
    const int half = tid >> 7;
    float acc = 0.f;
    const bf16* vp = Vm + base + d;
    for (int k = half * 512; k < half * 512 + 512; ++k)
        acc = fmaf(sc[k], __bfloat162float(vp[(size_t)k * DMODEL]), acc);
    if (half) red[d] = acc;
    __syncthreads();
    if (!half)
        Om[base + (size_t)q * DMODEL + d] = __float2bfloat16((acc + red[d]) * inv);
}

// ---------------------------------------------------------------------------
extern "C" void kernel_launch(void* const* d_in, const int* in_sizes, int n_in,
                              void* d_out, int out_size, void* d_ws, size_t ws_size,
                              hipStream_t stream) {
    const void* x     = d_in[0];
    const void* W1    = d_in[1];
    const void* b1    = d_in[2];
    const void* W2    = d_in[3];
    const void* b2    = d_in[4];
    const void* ln1_g = d_in[5];
    const void* ln1_b = d_in[6];
    const void* ln2_g = d_in[7];
    const void* ln2_b = d_in[8];
    const void* Wq    = d_in[9];
    const void* bq    = d_in[10];
    const void* Wk    = d_in[11];
    const void* bk    = d_in[12];
    const void* Wv    = d_in[13];
    const void* bv    = d_in[14];
    const void* Wo    = d_in[15];
    const void* bo    = d_in[16];
    const void* Fw1   = d_in[17];
    const void* Fb1   = d_in[18];
    const void* Fw2   = d_in[19];
    const void* Fb2   = d_in[20];

    // dtype probe (runs every call; deterministic)
    detect_kernel<<<1, 64, 0, stream>>>(W1);

    // batch-chunking: each batch needs 4 bf16 slabs of 1024x1024 = 8 MB ws
    int c = 8;
    while (c > 1 && (size_t)c * (8ull << 20) > ws_size) c >>= 1;
    const int nch = 8 / c;
    const int Mc = c * TSEQ;                    // rows per chunk
    const size_t SL = (size_t)Mc * DMODEL;      // scratch slab elements

    bf16* Hh = (bf16*)d_ws;
    bf16* Qb = Hh + SL;
    bf16* Kb = Qb + SL;
    bf16* Vb = Kb + SL;
    bf16* Hid = Qb;   // Mc x 2048 bf16 spans Qb+Kb
    bf16* Ffh = Qb;   // Mc x 256
    bf16* Ob  = Hh;   // attn output reuses LN buffer

    void* X = d_out;  // residual stream lives in d_out (flag dtype)

    dim3 blk2(16, 16);

    for (int ci = 0; ci < nch; ++ci) {
        const size_t roff = (size_t)ci * Mc * DMODEL;  // element offset (rows)

        // ---- downsample MLP ----
        gemm_kernel<1, 0, true, false><<<dim3(DFF / 64, Mc / 64), blk2, 0, stream>>>(
            x, roff, W1, 0, b1, 0, Hid, 0, Mc, DFF, DMODEL);
        gemm_kernel<0, 1, false, false><<<dim3(DMODEL / 64, Mc / 64), blk2, 0, stream>>>(
            Hid, 0, W2, 0, b2, 0, X, roff, Mc, DMODEL, DFF);

        for (int l = 0; l < 2; ++l) {
            const size_t wOff  = (size_t)l * DMODEL * DMODEL;
            const size_t vOff  = (size_t)l * DMODEL;
            const size_t f1wOff = (size_t)l * FHID * DMODEL;
            const size_t f1bOff = (size_t)l * FHID;

            ln_kernel<<<Mc, 256, 0, stream>>>(X, roff, ln1_g, ln1_b, vOff, Hh);
            gemm_kernel<0, 0, false, false><<<dim3(DMODEL / 64, Mc / 64), blk2, 0, stream>>>(
                Hh, 0, Wq, wOff, bq, vOff, Qb, 0, Mc, DMODEL, DMODEL);
            gemm_kernel<0, 0, false, false><<<dim3(DMODEL / 64, Mc / 64), blk2, 0, stream>>>(
                Hh, 0, Wk, wOff, bk, vOff, Kb, 0, Mc, DMODEL, DMODEL);
            gemm_kernel<0, 0, false, false><<<dim3(DMODEL / 64, Mc / 64), blk2, 0, stream>>>(
                Hh, 0, Wv, wOff, bv, vOff, Vb, 0, Mc, DMODEL, DMODEL);

            attn_kernel<<<dim3(TSEQ, NHEAD, c), 256, 0, stream>>>(Qb, Kb, Vb, Ob);

            gemm_kernel<0, 1, false, true><<<dim3(DMODEL / 64, Mc / 64), blk2, 0, stream>>>(
                Ob, 0, Wo, wOff, bo, vOff, X, roff, Mc, DMODEL, DMODEL);

            ln_kernel<<<Mc, 256, 0, stream>>>(X, roff, ln2_g, ln2_b, vOff, Hh);
            gemm_kernel<0, 0, true, false><<<dim3(FHID / 64, Mc / 64), blk2, 0, stream>>>(
                Hh, 0, Fw1, f1wOff, Fb1, f1bOff, Ffh, 0, Mc, FHID, DMODEL);
            gemm_kernel<0, 1, false, true><<<dim3(DMODEL / 64, Mc / 64), blk2, 0, stream>>>(
                Ffh, 0, Fw2, f1wOff, Fb2, vOff, X, roff, Mc, DMODEL, FHID);
        }
    }
}

// Round 4
// 2341.190 us; speedup vs baseline: 7.7957x; 7.7957x over previous
//
#include <hip/hip_runtime.h>
#include <hip/hip_bf16.h>

// ---------------------------------------------------------------------------
// CorrectTransformerAdaptor — Round 3: MFMA everywhere.
//   - gemm_mfma: 128x128 tile, BK=32, 4 waves, 4x4 16x16x32 bf16 MFMAs/wave,
//     dtype-flag staging (harness buffers may be f32 or bf16), fp32 accum.
//   - attn_mfma: flash-style, block = (qtile 64) x (head) x (batch);
//     K/V 64-key tiles in LDS (V transposed, XOR-swizzled), online softmax,
//     P via per-wave LDS round-trip (C-layout -> A-layout).
// Residual X in d_out (flag dtype); scratch always bf16; batch-chunked.
// ---------------------------------------------------------------------------

#define DMODEL 1024
#define DFF 2048
#define FHID 256
#define NHEAD 8
#define DKH 128
#define TSEQ 1024

typedef __hip_bfloat16 bf16;
typedef __attribute__((ext_vector_type(8))) short bf16x8;   // 8 bf16 = 4 VGPR
typedef __attribute__((ext_vector_type(4))) float f32x4;

#define MFMA16(a, b, c) __builtin_amdgcn_mfma_f32_16x16x32_bf16(a, b, c, 0, 0, 0)

__device__ int g_is_bf16;

__device__ __forceinline__ bool flagbf() {
    return __hip_atomic_load(&g_is_bf16, __ATOMIC_ACQUIRE,
                             __HIP_MEMORY_SCOPE_AGENT) != 0;
}
__device__ __forceinline__ float gload(const void* p, size_t i, bool bf) {
    return bf ? __bfloat162float(((const bf16*)p)[i]) : ((const float*)p)[i];
}
__device__ __forceinline__ void gstore(void* p, size_t i, bool bf, float v) {
    if (bf) ((bf16*)p)[i] = __float2bfloat16(v);
    else    ((float*)p)[i] = v;
}
// 16 consecutive elements -> bf16[16], vectorized for both dtypes.
__device__ __forceinline__ void load16(const void* p, size_t off, bool bf, bf16* dst) {
    if (bf) {
        const uint4* s = (const uint4*)((const bf16*)p + off);
        ((uint4*)dst)[0] = s[0];
        ((uint4*)dst)[1] = s[1];
    } else {
        const float4* s = (const float4*)((const float*)p + off);
        #pragma unroll
        for (int g = 0; g < 4; ++g) {
            float4 f = s[g];
            dst[g * 4 + 0] = __float2bfloat16(f.x);
            dst[g * 4 + 1] = __float2bfloat16(f.y);
            dst[g * 4 + 2] = __float2bfloat16(f.z);
            dst[g * 4 + 3] = __float2bfloat16(f.w);
        }
    }
}

// ---- dtype probe ----------------------------------------------------------
__global__ void detect_kernel(const void* __restrict__ probe) {
    if (threadIdx.x == 0 && blockIdx.x == 0) {
        const bf16* h = (const bf16*)probe;
        int isbf = 1;
        for (int i = 0; i < 256; ++i) {
            float v = __bfloat162float(h[i]);
            if (!(fabsf(v) <= 1000.0f)) isbf = 0;
        }
        __hip_atomic_store(&g_is_bf16, isbf, __ATOMIC_RELEASE,
                           __HIP_MEMORY_SCOPE_AGENT);
    }
}

// ---------------- block reduction (256-thread blocks, LN only) -------------
__device__ __forceinline__ float block_reduce_sum(float v, float* red) {
    int tid = threadIdx.x;
    red[tid] = v;
    __syncthreads();
    #pragma unroll
    for (int s = 128; s > 0; s >>= 1) {
        if (tid < s) red[tid] += red[tid + s];
        __syncthreads();
    }
    float r = red[0];
    __syncthreads();
    return r;
}

// ---------------- MFMA GEMM: C[M,N] = op(A[M,K] @ W[N,K]^T + bias) ---------
// AMODE/CMODE: 0 = fixed bf16 scratch, 1 = flag-dtype harness buffer.
template <int AMODE, int CMODE, bool RELU, bool ADD>
__global__ __launch_bounds__(256) void gemm_mfma(
        const void* __restrict__ A, size_t a_off,
        const void* __restrict__ W, size_t w_off,
        const void* __restrict__ bias, size_t b_off,
        void* __restrict__ C, size_t c_off,
        int M, int N, int K) {
    const bool fl  = flagbf();
    const bool abf = AMODE ? fl : true;
    const bool cbf = CMODE ? fl : true;

    __shared__ __align__(16) bf16 As[128][32];
    __shared__ __align__(16) bf16 Bs[128][32];

    const int bm = blockIdx.y * 128, bn = blockIdx.x * 128;
    const int tid = threadIdx.x;
    const int wave = tid >> 6, lane = tid & 63;
    const int quad = lane >> 4, l15 = lane & 15;
    const int wr = wave >> 1, wc = wave & 1;   // 2x2 wave grid of 64x64

    f32x4 acc[4][4];
    #pragma unroll
    for (int i = 0; i < 4; ++i)
        #pragma unroll
        for (int j = 0; j < 4; ++j) acc[i][j] = (f32x4){0.f, 0.f, 0.f, 0.f};

    const int r = tid >> 1, seg = (tid & 1) * 16;

    for (int k0 = 0; k0 < K; k0 += 32) {
        __syncthreads();   // previous iteration's frag reads done
        bf16 ta[16], tb[16];
        load16(A, a_off + (size_t)(bm + r) * K + k0 + seg, abf, ta);
        load16(W, w_off + (size_t)(bn + r) * K + k0 + seg, fl, tb);
        *(uint4*)&As[r][seg]     = ((uint4*)ta)[0];
        *(uint4*)&As[r][seg + 8] = ((uint4*)ta)[1];
        *(uint4*)&Bs[r][seg]     = ((uint4*)tb)[0];
        *(uint4*)&Bs[r][seg + 8] = ((uint4*)tb)[1];
        __syncthreads();

        bf16x8 af[4], bfr[4];
        #pragma unroll
        for (int mi = 0; mi < 4; ++mi)
            af[mi] = *(const bf16x8*)&As[wr * 64 + mi * 16 + l15][quad * 8];
        #pragma unroll
        for (int ni = 0; ni < 4; ++ni)
            bfr[ni] = *(const bf16x8*)&Bs[wc * 64 + ni * 16 + l15][quad * 8];
        #pragma unroll
        for (int mi = 0; mi < 4; ++mi)
            #pragma unroll
            for (int ni = 0; ni < 4; ++ni)
                acc[mi][ni] = MFMA16(af[mi], bfr[ni], acc[mi][ni]);
    }

    // epilogue: C row = quad*4+reg, col = lane&15 (verified m89/m91 layout)
    #pragma unroll
    for (int ni = 0; ni < 4; ++ni) {
        const int col = bn + wc * 64 + ni * 16 + l15;
        const float bv = gload(bias, b_off + col, fl);
        #pragma unroll
        for (int mi = 0; mi < 4; ++mi) {
            const int row0 = bm + wr * 64 + mi * 16 + quad * 4;
            #pragma unroll
            for (int rr = 0; rr < 4; ++rr) {
                float v = acc[mi][ni][rr] + bv;
                if (RELU) v = fmaxf(v, 0.f);
                size_t idx = c_off + (size_t)(row0 + rr) * N + col;
                if (ADD) v += gload(C, idx, cbf);
                gstore(C, idx, cbf, v);
            }
        }
    }
}

// ---------------- LayerNorm (row of 1024 per block) ------------------------
__global__ __launch_bounds__(256) void ln_kernel(
        const void* __restrict__ X, size_t x_off,
        const void* __restrict__ g, const void* __restrict__ b, size_t gb_off,
        bf16* __restrict__ H) {
    const bool fl = flagbf();
    const int D = DMODEL;
    __shared__ float xs[DMODEL];
    __shared__ float red[256];
    const int row = blockIdx.x, tid = threadIdx.x;
    const size_t xrow = x_off + (size_t)row * D;

    float s = 0.f;
    for (int i = tid; i < D; i += 256) { float v = gload(X, xrow + i, fl); xs[i] = v; s += v; }
    float mean = block_reduce_sum(s, red) * (1.f / D);

    float vs = 0.f;
    for (int i = tid; i < D; i += 256) { float d = xs[i] - mean; vs += d * d; }
    float var = block_reduce_sum(vs, red) * (1.f / D);
    float rstd = rsqrtf(var + 1e-12f);

    bf16* h = H + (size_t)row * D;
    for (int i = tid; i < D; i += 256)
        h[i] = __float2bfloat16((xs[i] - mean) * rstd * gload(g, gb_off + i, fl)
                                + gload(b, gb_off + i, fl));
}

// ---------------- Flash-style MFMA attention -------------------------------
// Grid: (TSEQ/64, NHEAD, c). Block: 256 threads = 4 waves, wave w owns
// q-rows [qt*64 + w*16, +16). K loop over 64-key tiles staged in LDS.
__global__ __launch_bounds__(256) void attn_mfma(
        const bf16* __restrict__ Qm, const bf16* __restrict__ Km,
        const bf16* __restrict__ Vm, bf16* __restrict__ Om) {
    const int qt = blockIdx.x, h = blockIdx.y, bb = blockIdx.z;
    const int tid = threadIdx.x;
    const int wave = tid >> 6, lane = tid & 63;
    const int quad = lane >> 4, l15 = lane & 15;

    // Kt[key][d] with d 8-blocks XOR-swizzled by key&7 (bank spread).
    // Vt[d][key] transposed, key 8-blocks XOR-swizzled by d&7.
    // Ps: per-wave P (16 q x 64 key), row stride 72 (aligned + bank spread).
    __shared__ __align__(16) bf16 Kt[64][128];
    __shared__ __align__(16) bf16 Vt[128][64];
    __shared__ __align__(16) bf16 Ps[4][16][72];

    const size_t base = ((size_t)bb * TSEQ) * DMODEL + (size_t)h * DKH;
    const int qrow = qt * 64 + wave * 16 + l15;
    const float scale = 0.08838834764831845f;  // 1/sqrt(128)

    // Q fragments (A-operand: m=lane&15, k=quad*8+j), scale folded in.
    bf16x8 qf[4];
    #pragma unroll
    for (int kc = 0; kc < 4; ++kc) {
        uint4 raw = *(const uint4*)(Qm + base + (size_t)qrow * DMODEL + kc * 32 + quad * 8);
        const bf16* rb = (const bf16*)&raw;
        bf16 tmp[8];
        #pragma unroll
        for (int j = 0; j < 8; ++j)
            tmp[j] = __float2bfloat16(__bfloat162float(rb[j]) * scale);
        qf[kc] = *(const bf16x8*)tmp;
    }

    f32x4 o[8];
    #pragma unroll
    for (int i = 0; i < 8; ++i) o[i] = (f32x4){0.f, 0.f, 0.f, 0.f};
    float m_i[4] = {-1e30f, -1e30f, -1e30f, -1e30f};
    float l_i[4] = {0.f, 0.f, 0.f, 0.f};

    const int skey = tid >> 2;            // staging: key row 0..63
    const int dseg = (tid & 3) * 32;      // 32 consecutive d per thread
    const int skey3 = skey >> 3, sk7 = skey & 7;

    for (int kt = 0; kt < TSEQ / 64; ++kt) {
        __syncthreads();   // previous tile's LDS reads done
        {
            const bf16* kp = Km + base + (size_t)(kt * 64 + skey) * DMODEL + dseg;
            const bf16* vp = Vm + base + (size_t)(kt * 64 + skey) * DMODEL + dseg;
            uint4 kv[4], vv[4];
            #pragma unroll
            for (int g = 0; g < 4; ++g) { kv[g] = ((const uint4*)kp)[g]; vv[g] = ((const uint4*)vp)[g]; }
            #pragma unroll
            for (int g = 0; g < 4; ++g) {
                int d3 = (dseg >> 3) + g;
                *(uint4*)&Kt[skey][(d3 ^ sk7) << 3] = kv[g];
            }
            const bf16* vsrc = (const bf16*)vv;
            #pragma unroll
            for (int j = 0; j < 32; ++j) {
                int d = dseg + j;
                Vt[d][((skey3 ^ (d & 7)) << 3) | sk7] = vsrc[j];
            }
        }
        __syncthreads();

        // ---- S = Q K^T (16 q x 64 key per wave) ----
        f32x4 s[4];
        #pragma unroll
        for (int ni = 0; ni < 4; ++ni) s[ni] = (f32x4){0.f, 0.f, 0.f, 0.f};
        #pragma unroll
        for (int ni = 0; ni < 4; ++ni) {
            const int key = ni * 16 + l15;     // B-operand n = lane&15
            #pragma unroll
            for (int kc = 0; kc < 4; ++kc) {
                const int d3 = kc * 4 + quad;  // B-operand k = quad*8+j
                bf16x8 kb = *(const bf16x8*)&Kt[key][(d3 ^ (key & 7)) << 3];
                s[ni] = MFMA16(qf[kc], kb, s[ni]);
            }
        }

        // ---- online softmax (rows quad*4+r live in this quad's 16 lanes) --
        float tm[4], al[4], ts[4];
        #pragma unroll
        for (int rr = 0; rr < 4; ++rr) {
            float v = fmaxf(fmaxf(s[0][rr], s[1][rr]), fmaxf(s[2][rr], s[3][rr]));
            v = fmaxf(v, __shfl_xor(v, 1));
            v = fmaxf(v, __shfl_xor(v, 2));
            v = fmaxf(v, __shfl_xor(v, 4));
            v = fmaxf(v, __shfl_xor(v, 8));
            tm[rr] = v;
        }
        #pragma unroll
        for (int rr = 0; rr < 4; ++rr) {
            float mn = fmaxf(m_i[rr], tm[rr]);
            al[rr] = __expf(m_i[rr] - mn);
            m_i[rr] = mn;
            ts[rr] = 0.f;
        }
        #pragma unroll
        for (int ni = 0; ni < 4; ++ni)
            #pragma unroll
            for (int rr = 0; rr < 4; ++rr) {
                float p = __expf(s[ni][rr] - m_i[rr]);
                s[ni][rr] = p;
                ts[rr] += p;
            }
        #pragma unroll
        for (int rr = 0; rr < 4; ++rr) {
            float v = ts[rr];
            v += __shfl_xor(v, 1);
            v += __shfl_xor(v, 2);
            v += __shfl_xor(v, 4);
            v += __shfl_xor(v, 8);
            l_i[rr] = l_i[rr] * al[rr] + v;
        }
        #pragma unroll
        for (int i = 0; i < 8; ++i)
            #pragma unroll
            for (int rr = 0; rr < 4; ++rr) o[i][rr] *= al[rr];

        // ---- P: C-layout -> LDS -> A-layout ----
        #pragma unroll
        for (int ni = 0; ni < 4; ++ni)
            #pragma unroll
            for (int rr = 0; rr < 4; ++rr)
                Ps[wave][quad * 4 + rr][ni * 16 + l15] = __float2bfloat16(s[ni][rr]);
        __asm__ __volatile__("s_waitcnt lgkmcnt(0)" ::: "memory");
        bf16x8 pa[2];
        #pragma unroll
        for (int kc2 = 0; kc2 < 2; ++kc2)
            pa[kc2] = *(const bf16x8*)&Ps[wave][l15][kc2 * 32 + quad * 8];

        // ---- O += P V (16 q x 128 d) ----
        #pragma unroll
        for (int ni2 = 0; ni2 < 8; ++ni2) {
            const int d = ni2 * 16 + l15;      // B-operand n = d-col
            #pragma unroll
            for (int kc2 = 0; kc2 < 2; ++kc2) {
                const int key3 = kc2 * 4 + quad;
                bf16x8 vb = *(const bf16x8*)&Vt[d][(key3 ^ (d & 7)) << 3];
                o[ni2] = MFMA16(pa[kc2], vb, o[ni2]);
            }
        }
    }

    // ---- write O / l ----
    #pragma unroll
    for (int ni2 = 0; ni2 < 8; ++ni2)
        #pragma unroll
        for (int rr = 0; rr < 4; ++rr) {
            int qr = qt * 64 + wave * 16 + quad * 4 + rr;
            Om[base + (size_t)qr * DMODEL + ni2 * 16 + l15] =
                __float2bfloat16(o[ni2][rr] / l_i[rr]);
        }
}

// ---------------------------------------------------------------------------
extern "C" void kernel_launch(void* const* d_in, const int* in_sizes, int n_in,
                              void* d_out, int out_size, void* d_ws, size_t ws_size,
                              hipStream_t stream) {
    const void* x     = d_in[0];
    const void* W1    = d_in[1];
    const void* b1    = d_in[2];
    const void* W2    = d_in[3];
    const void* b2    = d_in[4];
    const void* ln1_g = d_in[5];
    const void* ln1_b = d_in[6];
    const void* ln2_g = d_in[7];
    const void* ln2_b = d_in[8];
    const void* Wq    = d_in[9];
    const void* bq    = d_in[10];
    const void* Wk    = d_in[11];
    const void* bk    = d_in[12];
    const void* Wv    = d_in[13];
    const void* bv    = d_in[14];
    const void* Wo    = d_in[15];
    const void* bo    = d_in[16];
    const void* Fw1   = d_in[17];
    const void* Fb1   = d_in[18];
    const void* Fw2   = d_in[19];
    const void* Fb2   = d_in[20];

    detect_kernel<<<1, 64, 0, stream>>>(W1);

    int c = 8;
    while (c > 1 && (size_t)c * (8ull << 20) > ws_size) c >>= 1;
    const int nch = 8 / c;
    const int Mc = c * TSEQ;
    const size_t SL = (size_t)Mc * DMODEL;

    bf16* Hh = (bf16*)d_ws;
    bf16* Qb = Hh + SL;
    bf16* Kb = Qb + SL;
    bf16* Vb = Kb + SL;
    bf16* Hid = Qb;   // Mc x 2048 spans Qb+Kb
    bf16* Ffh = Qb;   // Mc x 256
    bf16* Ob  = Hh;   // attn output reuses LN buffer
    void* X = d_out;  // residual stream (flag dtype)

    for (int ci = 0; ci < nch; ++ci) {
        const size_t roff = (size_t)ci * Mc * DMODEL;

        gemm_mfma<1, 0, true, false><<<dim3(DFF / 128, Mc / 128), 256, 0, stream>>>(
            x, roff, W1, 0, b1, 0, Hid, 0, Mc, DFF, DMODEL);
        gemm_mfma<0, 1, false, false><<<dim3(DMODEL / 128, Mc / 128), 256, 0, stream>>>(
            Hid, 0, W2, 0, b2, 0, X, roff, Mc, DMODEL, DFF);

        for (int l = 0; l < 2; ++l) {
            const size_t wOff   = (size_t)l * DMODEL * DMODEL;
            const size_t vOff   = (size_t)l * DMODEL;
            const size_t f1wOff = (size_t)l * FHID * DMODEL;
            const size_t f1bOff = (size_t)l * FHID;

            ln_kernel<<<Mc, 256, 0, stream>>>(X, roff, ln1_g, ln1_b, vOff, Hh);
            gemm_mfma<0, 0, false, false><<<dim3(DMODEL / 128, Mc / 128), 256, 0, stream>>>(
                Hh, 0, Wq, wOff, bq, vOff, Qb, 0, Mc, DMODEL, DMODEL);
            gemm_mfma<0, 0, false, false><<<dim3(DMODEL / 128, Mc / 128), 256, 0, stream>>>(
                Hh, 0, Wk, wOff, bk, vOff, Kb, 0, Mc, DMODEL, DMODEL);
            gemm_mfma<0, 0, false, false><<<dim3(DMODEL / 128, Mc / 128), 256, 0, stream>>>(
                Hh, 0, Wv, wOff, bv, vOff, Vb, 0, Mc, DMODEL, DMODEL);

            attn_mfma<<<dim3(TSEQ / 64, NHEAD, c), 256, 0, stream>>>(Qb, Kb, Vb, Ob);

            gemm_mfma<0, 1, false, true><<<dim3(DMODEL / 128, Mc / 128), 256, 0, stream>>>(
                Ob, 0, Wo, wOff, bo, vOff, X, roff, Mc, DMODEL, DMODEL);

            ln_kernel<<<Mc, 256, 0, stream>>>(X, roff, ln2_g, ln2_b, vOff, Hh);
            gemm_mfma<0, 0, true, false><<<dim3(FHID / 128, Mc / 128), 256, 0, stream>>>(
                Hh, 0, Fw1, f1wOff, Fb1, f1bOff, Ffh, 0, Mc, FHID, DMODEL);
            gemm_mfma<0, 1, false, true><<<dim3(DMODEL / 128, Mc / 128), 256, 0, stream>>>(
                Ffh, 0, Fw2, f1wOff, Fb2, vOff, X, roff, Mc, DMODEL, FHID);
        }
    }
}

// Round 5
// 1621.059 us; speedup vs baseline: 11.2588x; 1.4442x over previous
//
#include <hip/hip_runtime.h>
#include <hip/hip_bf16.h>

// ---------------------------------------------------------------------------
// CorrectTransformerAdaptor — Round 4: fix latency-bound LayerNorm.
//   - ln_wave: one wave per row (1024 elems, 16/lane in registers),
//     __shfl_xor butterfly reductions, no LDS, no __syncthreads.
//   - detect_kernel parallelized (64 lanes + __ballot) — was 256 serial loads.
//   - gemm_mfma / attn_mfma unchanged from round 3 (passed, absmax 0.0156).
// ---------------------------------------------------------------------------

#define DMODEL 1024
#define DFF 2048
#define FHID 256
#define NHEAD 8
#define DKH 128
#define TSEQ 1024

typedef __hip_bfloat16 bf16;
typedef __attribute__((ext_vector_type(8))) short bf16x8;   // 8 bf16 = 4 VGPR
typedef __attribute__((ext_vector_type(4))) float f32x4;

#define MFMA16(a, b, c) __builtin_amdgcn_mfma_f32_16x16x32_bf16(a, b, c, 0, 0, 0)

__device__ int g_is_bf16;

__device__ __forceinline__ bool flagbf() {
    return __hip_atomic_load(&g_is_bf16, __ATOMIC_ACQUIRE,
                             __HIP_MEMORY_SCOPE_AGENT) != 0;
}
__device__ __forceinline__ float gload(const void* p, size_t i, bool bf) {
    return bf ? __bfloat162float(((const bf16*)p)[i]) : ((const float*)p)[i];
}
__device__ __forceinline__ void gstore(void* p, size_t i, bool bf, float v) {
    if (bf) ((bf16*)p)[i] = __float2bfloat16(v);
    else    ((float*)p)[i] = v;
}
// 16 consecutive elements -> bf16[16], vectorized for both dtypes.
__device__ __forceinline__ void load16(const void* p, size_t off, bool bf, bf16* dst) {
    if (bf) {
        const uint4* s = (const uint4*)((const bf16*)p + off);
        ((uint4*)dst)[0] = s[0];
        ((uint4*)dst)[1] = s[1];
    } else {
        const float4* s = (const float4*)((const float*)p + off);
        #pragma unroll
        for (int g = 0; g < 4; ++g) {
            float4 f = s[g];
            dst[g * 4 + 0] = __float2bfloat16(f.x);
            dst[g * 4 + 1] = __float2bfloat16(f.y);
            dst[g * 4 + 2] = __float2bfloat16(f.z);
            dst[g * 4 + 3] = __float2bfloat16(f.w);
        }
    }
}

// ---- dtype probe (64 lanes, ballot) ---------------------------------------
__global__ void detect_kernel(const void* __restrict__ probe) {
    const int lane = threadIdx.x & 63;
    const bf16* h = (const bf16*)probe;
    int ok = 1;
    #pragma unroll
    for (int j = 0; j < 4; ++j) {
        float v = __bfloat162float(h[lane * 4 + j]);
        if (!(fabsf(v) <= 1000.0f)) ok = 0;   // catches huge AND NaN
    }
    unsigned long long m = __ballot(ok);
    if (lane == 0)
        __hip_atomic_store(&g_is_bf16, m == ~0ull ? 1 : 0, __ATOMIC_RELEASE,
                           __HIP_MEMORY_SCOPE_AGENT);
}

// ---------------- MFMA GEMM: C[M,N] = op(A[M,K] @ W[N,K]^T + bias) ---------
// AMODE/CMODE: 0 = fixed bf16 scratch, 1 = flag-dtype harness buffer.
template <int AMODE, int CMODE, bool RELU, bool ADD>
__global__ __launch_bounds__(256) void gemm_mfma(
        const void* __restrict__ A, size_t a_off,
        const void* __restrict__ W, size_t w_off,
        const void* __restrict__ bias, size_t b_off,
        void* __restrict__ C, size_t c_off,
        int M, int N, int K) {
    const bool fl  = flagbf();
    const bool abf = AMODE ? fl : true;
    const bool cbf = CMODE ? fl : true;

    __shared__ __align__(16) bf16 As[128][32];
    __shared__ __align__(16) bf16 Bs[128][32];

    const int bm = blockIdx.y * 128, bn = blockIdx.x * 128;
    const int tid = threadIdx.x;
    const int wave = tid >> 6, lane = tid & 63;
    const int quad = lane >> 4, l15 = lane & 15;
    const int wr = wave >> 1, wc = wave & 1;   // 2x2 wave grid of 64x64

    f32x4 acc[4][4];
    #pragma unroll
    for (int i = 0; i < 4; ++i)
        #pragma unroll
        for (int j = 0; j < 4; ++j) acc[i][j] = (f32x4){0.f, 0.f, 0.f, 0.f};

    const int r = tid >> 1, seg = (tid & 1) * 16;

    for (int k0 = 0; k0 < K; k0 += 32) {
        __syncthreads();   // previous iteration's frag reads done
        bf16 ta[16], tb[16];
        load16(A, a_off + (size_t)(bm + r) * K + k0 + seg, abf, ta);
        load16(W, w_off + (size_t)(bn + r) * K + k0 + seg, fl, tb);
        *(uint4*)&As[r][seg]     = ((uint4*)ta)[0];
        *(uint4*)&As[r][seg + 8] = ((uint4*)ta)[1];
        *(uint4*)&Bs[r][seg]     = ((uint4*)tb)[0];
        *(uint4*)&Bs[r][seg + 8] = ((uint4*)tb)[1];
        __syncthreads();

        bf16x8 af[4], bfr[4];
        #pragma unroll
        for (int mi = 0; mi < 4; ++mi)
            af[mi] = *(const bf16x8*)&As[wr * 64 + mi * 16 + l15][quad * 8];
        #pragma unroll
        for (int ni = 0; ni < 4; ++ni)
            bfr[ni] = *(const bf16x8*)&Bs[wc * 64 + ni * 16 + l15][quad * 8];
        #pragma unroll
        for (int mi = 0; mi < 4; ++mi)
            #pragma unroll
            for (int ni = 0; ni < 4; ++ni)
                acc[mi][ni] = MFMA16(af[mi], bfr[ni], acc[mi][ni]);
    }

    // epilogue: C row = quad*4+reg, col = lane&15 (verified m89/m91 layout)
    #pragma unroll
    for (int ni = 0; ni < 4; ++ni) {
        const int col = bn + wc * 64 + ni * 16 + l15;
        const float bv = gload(bias, b_off + col, fl);
        #pragma unroll
        for (int mi = 0; mi < 4; ++mi) {
            const int row0 = bm + wr * 64 + mi * 16 + quad * 4;
            #pragma unroll
            for (int rr = 0; rr < 4; ++rr) {
                float v = acc[mi][ni][rr] + bv;
                if (RELU) v = fmaxf(v, 0.f);
                size_t idx = c_off + (size_t)(row0 + rr) * N + col;
                if (ADD) v += gload(C, idx, cbf);
                gstore(C, idx, cbf, v);
            }
        }
    }
}

// ---------------- LayerNorm: one wave per row, shuffle-only ----------------
__global__ __launch_bounds__(256) void ln_wave(
        const void* __restrict__ X, size_t x_off,
        const void* __restrict__ g, const void* __restrict__ b, size_t gb_off,
        bf16* __restrict__ H) {
    const bool fl = flagbf();
    const int lane = threadIdx.x & 63;
    const int row = blockIdx.x * 4 + (threadIdx.x >> 6);
    const size_t xrow = x_off + (size_t)row * DMODEL;

    float v[16];
    if (fl) {
        const bf16* xp = (const bf16*)X + xrow;
        #pragma unroll
        for (int c = 0; c < 2; ++c) {
            uint4 raw = *(const uint4*)(xp + c * 512 + lane * 8);
            const bf16* rb = (const bf16*)&raw;
            #pragma unroll
            for (int j = 0; j < 8; ++j) v[c * 8 + j] = __bfloat162float(rb[j]);
        }
    } else {
        const float* xp = (const float*)X + xrow;
        #pragma unroll
        for (int c = 0; c < 4; ++c) {
            float4 f = *(const float4*)(xp + c * 256 + lane * 4);
            v[c * 4 + 0] = f.x; v[c * 4 + 1] = f.y;
            v[c * 4 + 2] = f.z; v[c * 4 + 3] = f.w;
        }
    }

    float s = 0.f;
    #pragma unroll
    for (int j = 0; j < 16; ++j) s += v[j];
    #pragma unroll
    for (int off = 32; off > 0; off >>= 1) s += __shfl_xor(s, off);
    const float mean = s * (1.f / DMODEL);

    float vs = 0.f;
    #pragma unroll
    for (int j = 0; j < 16; ++j) { float d = v[j] - mean; vs += d * d; }
    #pragma unroll
    for (int off = 32; off > 0; off >>= 1) vs += __shfl_xor(vs, off);
    const float rstd = rsqrtf(vs * (1.f / DMODEL) + 1e-12f);

    bf16* h = H + (size_t)row * DMODEL;
    if (fl) {
        const bf16* gp = (const bf16*)g + gb_off;
        const bf16* bp = (const bf16*)b + gb_off;
        #pragma unroll
        for (int c = 0; c < 2; ++c) {
            const int o = c * 512 + lane * 8;
            uint4 gr = *(const uint4*)(gp + o);
            uint4 br = *(const uint4*)(bp + o);
            const bf16* gg = (const bf16*)&gr;
            const bf16* bb = (const bf16*)&br;
            bf16 outv[8];
            #pragma unroll
            for (int j = 0; j < 8; ++j)
                outv[j] = __float2bfloat16((v[c * 8 + j] - mean) * rstd *
                          __bfloat162float(gg[j]) + __bfloat162float(bb[j]));
            *(uint4*)(h + o) = *(const uint4*)outv;
        }
    } else {
        const float* gp = (const float*)g + gb_off;
        const float* bp = (const float*)b + gb_off;
        #pragma unroll
        for (int c = 0; c < 4; ++c) {
            const int o = c * 256 + lane * 4;
            float4 gr = *(const float4*)(gp + o);
            float4 br = *(const float4*)(bp + o);
            const float gg[4] = {gr.x, gr.y, gr.z, gr.w};
            const float bb[4] = {br.x, br.y, br.z, br.w};
            bf16 outv[4];
            #pragma unroll
            for (int j = 0; j < 4; ++j)
                outv[j] = __float2bfloat16((v[c * 4 + j] - mean) * rstd * gg[j] + bb[j]);
            *(uint2*)(h + o) = *(const uint2*)outv;
        }
    }
}

// ---------------- Flash-style MFMA attention -------------------------------
// Grid: (TSEQ/64, NHEAD, c). Block: 256 threads = 4 waves, wave w owns
// q-rows [qt*64 + w*16, +16). K loop over 64-key tiles staged in LDS.
__global__ __launch_bounds__(256) void attn_mfma(
        const bf16* __restrict__ Qm, const bf16* __restrict__ Km,
        const bf16* __restrict__ Vm, bf16* __restrict__ Om) {
    const int qt = blockIdx.x, h = blockIdx.y, bb = blockIdx.z;
    const int tid = threadIdx.x;
    const int wave = tid >> 6, lane = tid & 63;
    const int quad = lane >> 4, l15 = lane & 15;

    __shared__ __align__(16) bf16 Kt[64][128];
    __shared__ __align__(16) bf16 Vt[128][64];
    __shared__ __align__(16) bf16 Ps[4][16][72];

    const size_t base = ((size_t)bb * TSEQ) * DMODEL + (size_t)h * DKH;
    const int qrow = qt * 64 + wave * 16 + l15;
    const float scale = 0.08838834764831845f;  // 1/sqrt(128)

    bf16x8 qf[4];
    #pragma unroll
    for (int kc = 0; kc < 4; ++kc) {
        uint4 raw = *(const uint4*)(Qm + base + (size_t)qrow * DMODEL + kc * 32 + quad * 8);
        const bf16* rb = (const bf16*)&raw;
        bf16 tmp[8];
        #pragma unroll
        for (int j = 0; j < 8; ++j)
            tmp[j] = __float2bfloat16(__bfloat162float(rb[j]) * scale);
        qf[kc] = *(const bf16x8*)tmp;
    }

    f32x4 o[8];
    #pragma unroll
    for (int i = 0; i < 8; ++i) o[i] = (f32x4){0.f, 0.f, 0.f, 0.f};
    float m_i[4] = {-1e30f, -1e30f, -1e30f, -1e30f};
    float l_i[4] = {0.f, 0.f, 0.f, 0.f};

    const int skey = tid >> 2;
    const int dseg = (tid & 3) * 32;
    const int skey3 = skey >> 3, sk7 = skey & 7;

    for (int kt = 0; kt < TSEQ / 64; ++kt) {
        __syncthreads();
        {
            const bf16* kp = Km + base + (size_t)(kt * 64 + skey) * DMODEL + dseg;
            const bf16* vp = Vm + base + (size_t)(kt * 64 + skey) * DMODEL + dseg;
            uint4 kv[4], vv[4];
            #pragma unroll
            for (int g = 0; g < 4; ++g) { kv[g] = ((const uint4*)kp)[g]; vv[g] = ((const uint4*)vp)[g]; }
            #pragma unroll
            for (int g = 0; g < 4; ++g) {
                int d3 = (dseg >> 3) + g;
                *(uint4*)&Kt[skey][(d3 ^ sk7) << 3] = kv[g];
            }
            const bf16* vsrc = (const bf16*)vv;
            #pragma unroll
            for (int j = 0; j < 32; ++j) {
                int d = dseg + j;
                Vt[d][((skey3 ^ (d & 7)) << 3) | sk7] = vsrc[j];
            }
        }
        __syncthreads();

        f32x4 s[4];
        #pragma unroll
        for (int ni = 0; ni < 4; ++ni) s[ni] = (f32x4){0.f, 0.f, 0.f, 0.f};
        #pragma unroll
        for (int ni = 0; ni < 4; ++ni) {
            const int key = ni * 16 + l15;
            #pragma unroll
            for (int kc = 0; kc < 4; ++kc) {
                const int d3 = kc * 4 + quad;
                bf16x8 kb = *(const bf16x8*)&Kt[key][(d3 ^ (key & 7)) << 3];
                s[ni] = MFMA16(qf[kc], kb, s[ni]);
            }
        }

        float tm[4], al[4], ts[4];
        #pragma unroll
        for (int rr = 0; rr < 4; ++rr) {
            float v = fmaxf(fmaxf(s[0][rr], s[1][rr]), fmaxf(s[2][rr], s[3][rr]));
            v = fmaxf(v, __shfl_xor(v, 1));
            v = fmaxf(v, __shfl_xor(v, 2));
            v = fmaxf(v, __shfl_xor(v, 4));
            v = fmaxf(v, __shfl_xor(v, 8));
            tm[rr] = v;
        }
        #pragma unroll
        for (int rr = 0; rr < 4; ++rr) {
            float mn = fmaxf(m_i[rr], tm[rr]);
            al[rr] = __expf(m_i[rr] - mn);
            m_i[rr] = mn;
            ts[rr] = 0.f;
        }
        #pragma unroll
        for (int ni = 0; ni < 4; ++ni)
            #pragma unroll
            for (int rr = 0; rr < 4; ++rr) {
                float p = __expf(s[ni][rr] - m_i[rr]);
                s[ni][rr] = p;
                ts[rr] += p;
            }
        #pragma unroll
        for (int rr = 0; rr < 4; ++rr) {
            float v = ts[rr];
            v += __shfl_xor(v, 1);
            v += __shfl_xor(v, 2);
            v += __shfl_xor(v, 4);
            v += __shfl_xor(v, 8);
            l_i[rr] = l_i[rr] * al[rr] + v;
        }
        #pragma unroll
        for (int i = 0; i < 8; ++i)
            #pragma unroll
            for (int rr = 0; rr < 4; ++rr) o[i][rr] *= al[rr];

        #pragma unroll
        for (int ni = 0; ni < 4; ++ni)
            #pragma unroll
            for (int rr = 0; rr < 4; ++rr)
                Ps[wave][quad * 4 + rr][ni * 16 + l15] = __float2bfloat16(s[ni][rr]);
        __asm__ __volatile__("s_waitcnt lgkmcnt(0)" ::: "memory");
        bf16x8 pa[2];
        #pragma unroll
        for (int kc2 = 0; kc2 < 2; ++kc2)
            pa[kc2] = *(const bf16x8*)&Ps[wave][l15][kc2 * 32 + quad * 8];

        #pragma unroll
        for (int ni2 = 0; ni2 < 8; ++ni2) {
            const int d = ni2 * 16 + l15;
            #pragma unroll
            for (int kc2 = 0; kc2 < 2; ++kc2) {
                const int key3 = kc2 * 4 + quad;
                bf16x8 vb = *(const bf16x8*)&Vt[d][(key3 ^ (d & 7)) << 3];
                o[ni2] = MFMA16(pa[kc2], vb, o[ni2]);
            }
        }
    }

    #pragma unroll
    for (int ni2 = 0; ni2 < 8; ++ni2)
        #pragma unroll
        for (int rr = 0; rr < 4; ++rr) {
            int qr = qt * 64 + wave * 16 + quad * 4 + rr;
            Om[base + (size_t)qr * DMODEL + ni2 * 16 + l15] =
                __float2bfloat16(o[ni2][rr] / l_i[rr]);
        }
}

// ---------------------------------------------------------------------------
extern "C" void kernel_launch(void* const* d_in, const int* in_sizes, int n_in,
                              void* d_out, int out_size, void* d_ws, size_t ws_size,
                              hipStream_t stream) {
    const void* x     = d_in[0];
    const void* W1    = d_in[1];
    const void* b1    = d_in[2];
    const void* W2    = d_in[3];
    const void* b2    = d_in[4];
    const void* ln1_g = d_in[5];
    const void* ln1_b = d_in[6];
    const void* ln2_g = d_in[7];
    const void* ln2_b = d_in[8];
    const void* Wq    = d_in[9];
    const void* bq    = d_in[10];
    const void* Wk    = d_in[11];
    const void* bk    = d_in[12];
    const void* Wv    = d_in[13];
    const void* bv    = d_in[14];
    const void* Wo    = d_in[15];
    const void* bo    = d_in[16];
    const void* Fw1   = d_in[17];
    const void* Fb1   = d_in[18];
    const void* Fw2   = d_in[19];
    const void* Fb2   = d_in[20];

    detect_kernel<<<1, 64, 0, stream>>>(W1);

    int c = 8;
    while (c > 1 && (size_t)c * (8ull << 20) > ws_size) c >>= 1;
    const int nch = 8 / c;
    const int Mc = c * TSEQ;
    const size_t SL = (size_t)Mc * DMODEL;

    bf16* Hh = (bf16*)d_ws;
    bf16* Qb = Hh + SL;
    bf16* Kb = Qb + SL;
    bf16* Vb = Kb + SL;
    bf16* Hid = Qb;   // Mc x 2048 spans Qb+Kb
    bf16* Ffh = Qb;   // Mc x 256
    bf16* Ob  = Hh;   // attn output reuses LN buffer
    void* X = d_out;  // residual stream (flag dtype)

    for (int ci = 0; ci < nch; ++ci) {
        const size_t roff = (size_t)ci * Mc * DMODEL;

        gemm_mfma<1, 0, true, false><<<dim3(DFF / 128, Mc / 128), 256, 0, stream>>>(
            x, roff, W1, 0, b1, 0, Hid, 0, Mc, DFF, DMODEL);
        gemm_mfma<0, 1, false, false><<<dim3(DMODEL / 128, Mc / 128), 256, 0, stream>>>(
            Hid, 0, W2, 0, b2, 0, X, roff, Mc, DMODEL, DFF);

        for (int l = 0; l < 2; ++l) {
            const size_t wOff   = (size_t)l * DMODEL * DMODEL;
            const size_t vOff   = (size_t)l * DMODEL;
            const size_t f1wOff = (size_t)l * FHID * DMODEL;
            const size_t f1bOff = (size_t)l * FHID;

            ln_wave<<<Mc / 4, 256, 0, stream>>>(X, roff, ln1_g, ln1_b, vOff, Hh);
            gemm_mfma<0, 0, false, false><<<dim3(DMODEL / 128, Mc / 128), 256, 0, stream>>>(
                Hh, 0, Wq, wOff, bq, vOff, Qb, 0, Mc, DMODEL, DMODEL);
            gemm_mfma<0, 0, false, false><<<dim3(DMODEL / 128, Mc / 128), 256, 0, stream>>>(
                Hh, 0, Wk, wOff, bk, vOff, Kb, 0, Mc, DMODEL, DMODEL);
            gemm_mfma<0, 0, false, false><<<dim3(DMODEL / 128, Mc / 128), 256, 0, stream>>>(
                Hh, 0, Wv, wOff, bv, vOff, Vb, 0, Mc, DMODEL, DMODEL);

            attn_mfma<<<dim3(TSEQ / 64, NHEAD, c), 256, 0, stream>>>(Qb, Kb, Vb, Ob);

            gemm_mfma<0, 1, false, true><<<dim3(DMODEL / 128, Mc / 128), 256, 0, stream>>>(
                Ob, 0, Wo, wOff, bo, vOff, X, roff, Mc, DMODEL, DMODEL);

            ln_wave<<<Mc / 4, 256, 0, stream>>>(X, roff, ln2_g, ln2_b, vOff, Hh);
            gemm_mfma<0, 0, true, false><<<dim3(FHID / 128, Mc / 128), 256, 0, stream>>>(
                Hh, 0, Fw1, f1wOff, Fb1, f1bOff, Ffh, 0, Mc, FHID, DMODEL);
            gemm_mfma<0, 1, false, true><<<dim3(DMODEL / 128, Mc / 128), 256, 0, stream>>>(
                Ffh, 0, Fw2, f1wOff, Fb2, vOff, X, roff, Mc, DMODEL, FHID);
        }
    }
}